// Round 9
// baseline (19.283 us; speedup 1.0000x reference)
//
#include <hip/hip_runtime.h>

typedef float v2 __attribute__((ext_vector_type(2)));

__device__ __forceinline__ float frcp(float x){ return __builtin_amdgcn_rcpf(x); }
__device__ __forceinline__ v2 rcp2(v2 a){ v2 r; r.x = frcp(a.x); r.y = frcp(a.y); return r; }
__device__ __forceinline__ v2 min2(v2 a, v2 b){ v2 r; r.x = fminf(a.x,b.x); r.y = fminf(a.y,b.y); return r; }
__device__ __forceinline__ v2 max2(v2 a, v2 b){ v2 r; r.x = fmaxf(a.x,b.x); r.y = fmaxf(a.y,b.y); return r; }

// Liang-Barsky clip of segment p0 + t*d, t in [0,1], vs box [lo,hi].
// id = 1/d (precomputed). Returns cross(P(t0),P(t1)) of kept piece, 0 if empty.
// (v2 arithmetic -> v_pk_{fma,mul,add}_f32; body verified bit-correct in R7.)
__device__ __forceinline__ float lb_edge(v2 p0, v2 d, v2 id, v2 lo, v2 hi)
{
    v2 ta = (lo - p0) * id;
    v2 tb = (hi - p0) * id;
    v2 tmn = min2(ta, tb);
    v2 tmx = max2(ta, tb);
    float t0 = fmaxf(fmaxf(tmn.x, tmn.y), 0.f);   // v_max3
    float t1 = fminf(fminf(tmx.x, tmx.y), 1.f);   // v_min3
    v2 pa = (v2){t0, t0} * d + p0;                // v_pk_fma
    v2 pb = (v2){t1, t1} * d + p0;
    float c = fmaf(pa.x, pb.y, -(pa.y * pb.x));
    return (t1 > t0) ? c : 0.f;
}

// Quad centered cb with half-edge vectors u,v (corners cb +- u +- v in ref CCW
// order), clipped vs axis-aligned box [lo,hi]. Green sum of kept sub-segments.
// Edge deltas are -2u, -2v, +2u, +2v -> 2 rcp2 total.
__device__ __forceinline__ float clip_quad(v2 cb, v2 u, v2 v, v2 lo, v2 hi)
{
    v2 up = u + v, um = u - v;
    v2 g0 = cb + up, g1 = cb - um, g2 = cb - up, g3 = cb + um;
    v2 du2 = u + u, dv2 = v + v;
    v2 idu = rcp2(du2), idv = rcp2(dv2);
    float s = lb_edge(g0, -du2, -idu, lo, hi);
    s += lb_edge(g1, -dv2, -idv, lo, hi);
    s += lb_edge(g2,  du2,  idu, lo, hi);
    s += lb_edge(g3,  dv2,  idv, lo, hi);
    return s;
}

// 64-thread (single-wave) blocks: ~2 generations of blocks per CU at the
// 16-wg/CU cap -> gen-2 HBM burst overlaps gen-1 compute; no barrier/LDS in
// the block reduction.
__global__ __launch_bounds__(64) void giou_partial_kernel(
    const float* __restrict__ pred, const float* __restrict__ target,
    float* __restrict__ partial, int n)
{
    int i = blockIdx.x * 64 + threadIdx.x;
    bool active = (i < n);
    int j = active ? i : 0;

    const float p0 = pred[5*j+0], p1 = pred[5*j+1], p2 = pred[5*j+2], p3 = pred[5*j+3], p4 = pred[5*j+4];
    const float q0 = target[5*j+0], q1 = target[5*j+1], q2 = target[5*j+2], q3 = target[5*j+3], q4 = target[5*j+4];

    float loss = 0.0f;
    if (active) {
        const float hw1 = 0.5f*p2, hh1 = 0.5f*p3, hw2 = 0.5f*q2, hh2 = 0.5f*q3;
        const v2 oa = { 0.5f*(p0 - q0), 0.5f*(p1 - q1) };   // A center rel. midpoint (B = -oa)

        const float cs1 = __cosf(p4), sn1 = __sinf(p4);
        const float cs2 = __cosf(q4), sn2 = __sinf(q4);
        const float cD = cs1*cs2 + sn1*sn2;   // cos(a2-a1)
        const float sD = sn2*cs1 - cs2*sn1;   // sin(a2-a1)

        // ---- frame A (world rotated by -a1): A center caA, B center -caA ----
        const v2 caA = oa.x * (v2){cs1, -sn1} + oa.y * (v2){sn1, cs1};
        const v2 hA  = {hw1, hh1};
        float twoA = clip_quad(-caA,
                               hw2 * (v2){cD, sD}, hh2 * (v2){-sD, cD},
                               caA - hA, caA + hA);

        // ---- frame B (world rotated by -a2): A center caB, box B at -caB ----
        const v2 caB = oa.x * (v2){cs2, -sn2} + oa.y * (v2){sn2, cs2};
        const v2 hB  = {hw2, hh2};
        twoA += clip_quad(caB,
                          hw1 * (v2){cD, -sD}, hh1 * (v2){sD, cD},
                          -caB - hB, -caB + hB);

        float inter_area = 0.5f * fabsf(twoA);

        // ---- union / iou ----
        float unionv = p2*p3 + q2*q3 - inter_area;
        float iou = fmaxf(inter_area * frcp(unionv), 1e-6f);

        // ---- smallest enclosing rect: 2 distinct dirs, closed form ----
        float acd = fabsf(cD), asd = fabsf(sD);
        float eBx = hw2*acd + hh2*asd, eBy = hw2*asd + hh2*acd;
        float w1 = fmaxf(caA.x + hw1, -caA.x + eBx) - fminf(caA.x - hw1, -caA.x - eBx);
        float h1 = fmaxf(caA.y + hh1, -caA.y + eBy) - fminf(caA.y - hh1, -caA.y - eBy);
        float a1 = w1*h1;
        float eAx = hw1*acd + hh1*asd, eAy = hw1*asd + hh1*acd;
        float w2 = fmaxf(caB.x + eAx, -caB.x + hw2) - fminf(caB.x - eAx, -caB.x - hw2);
        float h2 = fmaxf(caB.y + eAy, -caB.y + hh2) - fminf(caB.y - eAy, -caB.y - hh2);
        float a2 = w2*h2;

        float area_c = (a2 < a1) ? a2 : a1;   // box1 dirs first in ref argmin

        float r = (area_c - unionv) * frcp(area_c);
        float giou = iou*iou*iou - r*r*r;
        loss = 1.0f - giou;
    }

    // ---- single-wave reduction: shuffles only, no barrier, no LDS ----
    #pragma unroll
    for (int off = 32; off; off >>= 1) loss += __shfl_down(loss, off, 64);
    if (threadIdx.x == 0) partial[blockIdx.x] = loss;
}

__global__ __launch_bounds__(256) void reduce_final_kernel(
    const float* __restrict__ partial, int nb, float* __restrict__ out, float invn)
{
    float s = 0.f;
    for (int i = threadIdx.x; i < nb; i += 256) s += partial[i];
    #pragma unroll
    for (int off = 32; off; off >>= 1) s += __shfl_down(s, off, 64);
    __shared__ float smem[4];
    int lane = threadIdx.x & 63, wid = threadIdx.x >> 6;
    if (lane == 0) smem[wid] = s;
    __syncthreads();
    if (threadIdx.x == 0) {
        out[0] = (smem[0] + smem[1] + smem[2] + smem[3]) * invn;
    }
}

extern "C" void kernel_launch(void* const* d_in, const int* in_sizes, int n_in,
                              void* d_out, int out_size, void* d_ws, size_t ws_size,
                              hipStream_t stream) {
    const float* pred   = (const float*)d_in[0];
    const float* target = (const float*)d_in[1];
    float* out = (float*)d_out;
    float* partial = (float*)d_ws;
    int n  = in_sizes[0] / 5;
    int nb = (n + 63) / 64;
    giou_partial_kernel<<<nb, 64, 0, stream>>>(pred, target, partial, n);
    reduce_final_kernel<<<1, 256, 0, stream>>>(partial, nb, out, 1.0f/(float)n);
}

// Round 10
// 12.934 us; speedup vs baseline: 1.4909x; 1.4909x over previous
//
#include <hip/hip_runtime.h>

__device__ __forceinline__ float frcp(float x){ return __builtin_amdgcn_rcpf(x); }

// Liang-Barsky t-interval length for segment p0 + t*d, t in [0,1], vs
// axis-aligned box [lx,hx]x[ly,hy]. id = 1/d precomputed. Returns
// clamp(t1-t0, 0) (0 when the segment misses the box).
__device__ __forceinline__ float lb_dt(float x0, float y0,
                                       float idx, float idy,
                                       float lx, float hx, float ly, float hy)
{
    float ta = (lx - x0) * idx, tb = (hx - x0) * idx;
    float tc = (ly - y0) * idy, td = (hy - y0) * idy;
    float t0 = fmaxf(fmaxf(fminf(ta, tb), fminf(tc, td)), 0.f);  // v_max3
    float t1 = fminf(fminf(fmaxf(ta, tb), fmaxf(tc, td)), 1.f);  // v_min3
    return fmaxf(t1 - t0, 0.f);
}

// Quad centered cb, corners cb +- u +- v (ref CCW order), clipped vs box
// [lo,hi]. Green-sum contribution in AREA units via the identity
// cross(P(t0),P(t1)) = (t1-t0)*cross(p0,d), with per-edge cross(p0,d)/2
// collapsing to {cuv-cu, cuv-cv, cuv+cu, cuv+cv}.
__device__ __forceinline__ float clip_quad(float cbx, float cby,
                                           float ux, float uy, float vx, float vy,
                                           float lx, float hx, float ly, float hy)
{
    float upx = ux + vx, upy = uy + vy;
    float umx = ux - vx, umy = uy - vy;
    float g0x = cbx + upx, g0y = cby + upy;   // +u+v  (edge d = -2u)
    float g1x = cbx - umx, g1y = cby - umy;   // -u+v  (edge d = -2v)
    float g2x = cbx - upx, g2y = cby - upy;   // -u-v  (edge d = +2u)
    float g3x = cbx + umx, g3y = cby + umy;   // +u-v  (edge d = +2v)

    float iux = frcp(ux + ux), iuy = frcp(uy + uy);   // 1/(2u)
    float ivx = frcp(vx + vx), ivy = frcp(vy + vy);   // 1/(2v)

    float cu  = fmaf(cbx, uy, -cby * ux);   // cross(cb,u)
    float cv  = fmaf(cbx, vy, -cby * vx);   // cross(cb,v)
    float cuv = fmaf(ux,  vy, -uy  * vx);   // cross(u,v) > 0 (CCW)

    float s;
    s  = lb_dt(g0x, g0y, -iux, -iuy, lx, hx, ly, hy) * (cuv - cu);
    s += lb_dt(g1x, g1y, -ivx, -ivy, lx, hx, ly, hy) * (cuv - cv);
    s += lb_dt(g2x, g2y,  iux,  iuy, lx, hx, ly, hy) * (cuv + cu);
    s += lb_dt(g3x, g3y,  ivx,  ivy, lx, hx, ly, hy) * (cuv + cv);
    return s;   // signed area contribution (full containment -> 4*cuv = Area)
}

__global__ __launch_bounds__(256) void giou_partial_kernel(
    const float* __restrict__ pred, const float* __restrict__ target,
    float* __restrict__ partial, int n)
{
    int i = blockIdx.x * blockDim.x + threadIdx.x;
    float loss = 0.0f;
    if (i < n) {
        const float p0 = pred[5*i+0], p1 = pred[5*i+1], p2 = pred[5*i+2], p3 = pred[5*i+3], p4 = pred[5*i+4];
        const float q0 = target[5*i+0], q1 = target[5*i+1], q2 = target[5*i+2], q3 = target[5*i+3], q4 = target[5*i+4];

        // A center relative to midpoint of centers; B center is exactly -oa
        const float oaX = 0.5f*(p0 - q0), oaY = 0.5f*(p1 - q1);
        const float hw1 = 0.5f*p2, hh1 = 0.5f*p3, hw2 = 0.5f*q2, hh2 = 0.5f*q3;

        const float cs1 = __cosf(p4), sn1 = __sinf(p4);
        const float cs2 = __cosf(q4), sn2 = __sinf(q4);
        const float cD = cs1*cs2 + sn1*sn2;   // cos(a2-a1)
        const float sD = sn2*cs1 - cs2*sn1;   // sin(a2-a1)

        // ---- frame A (rotate world by -a1, origin = midpoint) ----
        const float caX =  oaX*cs1 + oaY*sn1;
        const float caY = -oaX*sn1 + oaY*cs1;
        // B quad in frame A: center -ca, u = R(D)(hw2,0), v = R(D)(0,hh2)
        float S = clip_quad(-caX, -caY,
                            cD*hw2,  sD*hw2, -sD*hh2, cD*hh2,
                            caX - hw1, caX + hw1, caY - hh1, caY + hh1);

        // ---- frame B (rotate world by -a2) ----
        const float caX2 =  oaX*cs2 + oaY*sn2;
        const float caY2 = -oaX*sn2 + oaY*cs2;
        // A quad in frame B: center +ca2, u = R(-D)(hw1,0), v = R(-D)(0,hh1)
        S += clip_quad(caX2, caY2,
                       cD*hw1, -sD*hw1, sD*hh1, cD*hh1,
                       -caX2 - hw2, -caX2 + hw2, -caY2 - hh2, -caY2 + hh2);

        float inter_area = fabsf(S);

        // ---- union / iou ----
        float unionv = p2*p3 + q2*q3 - inter_area;
        float iou = fmaxf(inter_area * frcp(unionv), 1e-6f);

        // ---- smallest enclosing rect: 2 distinct directions, closed form ----
        float acd = fabsf(cD), asd = fabsf(sD);
        float eBx = hw2*acd + hh2*asd, eBy = hw2*asd + hh2*acd;
        float w1 = fmaxf(caX + hw1, -caX + eBx) - fminf(caX - hw1, -caX - eBx);
        float h1 = fmaxf(caY + hh1, -caY + eBy) - fminf(caY - hh1, -caY - eBy);
        float a1 = w1*h1;
        float eAx = hw1*acd + hh1*asd, eAy = hw1*asd + hh1*acd;
        float w2 = fmaxf(caX2 + eAx, -caX2 + hw2) - fminf(caX2 - eAx, -caX2 - hw2);
        float h2 = fmaxf(caY2 + eAy, -caY2 + hh2) - fminf(caY2 - eAy, -caY2 - hh2);
        float a2 = w2*h2;

        float area_c = (a2 < a1) ? a2 : a1;   // box1 dirs first in ref argmin

        float r = (area_c - unionv) * frcp(area_c);
        float giou = iou*iou*iou - r*r*r;
        loss = 1.0f - giou;
    }

    // ---- deterministic block reduction ----
    #pragma unroll
    for (int off = 32; off; off >>= 1) loss += __shfl_down(loss, off, 64);
    __shared__ float smem[4];
    int lane = threadIdx.x & 63, wid = threadIdx.x >> 6;
    if (lane == 0) smem[wid] = loss;
    __syncthreads();
    if (threadIdx.x == 0) {
        partial[blockIdx.x] = smem[0] + smem[1] + smem[2] + smem[3];
    }
}

// 1024 threads, one guarded float2 load per thread covers up to 2048 partials
// in a single memory round (nb = 1954 for N = 500k).
__global__ __launch_bounds__(1024) void reduce_final_kernel(
    const float* __restrict__ partial, int nb, float* __restrict__ out, float invn)
{
    int t = threadIdx.x;
    float s = 0.f;
    for (int i2 = t * 2; i2 < nb; i2 += 2048) {
        if (i2 + 1 < nb) { float2 v = *(const float2*)(partial + i2); s += v.x + v.y; }
        else             { s += partial[i2]; }
    }
    #pragma unroll
    for (int off = 32; off; off >>= 1) s += __shfl_down(s, off, 64);
    __shared__ float smem[16];
    int lane = t & 63, wid = t >> 6;
    if (lane == 0) smem[wid] = s;
    __syncthreads();
    if (t == 0) {
        float tot = 0.f;
        #pragma unroll
        for (int k = 0; k < 16; k++) tot += smem[k];
        out[0] = tot * invn;
    }
}

extern "C" void kernel_launch(void* const* d_in, const int* in_sizes, int n_in,
                              void* d_out, int out_size, void* d_ws, size_t ws_size,
                              hipStream_t stream) {
    const float* pred   = (const float*)d_in[0];
    const float* target = (const float*)d_in[1];
    float* out = (float*)d_out;
    float* partial = (float*)d_ws;
    int n  = in_sizes[0] / 5;
    int nb = (n + 255) / 256;
    giou_partial_kernel<<<nb, 256, 0, stream>>>(pred, target, partial, n);
    reduce_final_kernel<<<1, 1024, 0, stream>>>(partial, nb, out, 1.0f/(float)n);
}